// Round 1
// baseline (510.890 us; speedup 1.0000x reference)
//
#include <hip/hip_runtime.h>
#include <cstdint>

// VAE fused forward, MI355X/gfx950 — f32 in / f32 out.
// N=65536 rows, IO=64, HID=60, LAT=32, T=8.
// Round 5 restructure: split the monolithic 1-wave/SIMD kernel (2527 us) into
//   A) encoder: 1 thread/row -> mu/logvar   (256 blk x 256 thr, 1024 waves)
//   B) trajectories: 1 thread/(n,t)         (2048 blk x 256 thr, 8192 waves,
//      __launch_bounds__(256,4) => VGPR<=128, ~4 waves/SIMD)
// All arithmetic (loop order, fmaf chains, threefry, erfinv, expf) is
// bit-identical to the verified round-4 kernel; B re-reads mu/logvar from the
// output buffer (kernel-boundary coherence) and recomputes sd=expf(0.5*lv).
// RNG: JAX partitionable threefry, key (0,1): per flat index i,
//   bits = o0^o1 of threefry2x32(c0=0, c1=i);
//   u = max(lo,(f32(bits>>9|0x3F800000)-1)*2+lo), eps = sqrt(2)*erfinvf(u).
// Output (f32): traj[8][16][65536][4] @0 | mu[65536][32] @33554432 |
//   logvar[65536][32] @35651584 | prob[8][4096][16] @37748736 (== 0.125f).

#define TPB_A 256
#define NBLK_A 256
#define TPB_B 256
#define NBLK_B 2048

// JAX threefry2x32 with key (0,1): ks = {0, 1, 0^1^0x1BD11BDA = 0x1BD11BDB}
__device__ __forceinline__ void threefry2x32_01(uint32_t c0, uint32_t c1,
                                                uint32_t& o0, uint32_t& o1) {
  uint32_t x0 = c0;        // + ks0 (0)
  uint32_t x1 = c1 + 1u;   // + ks1 (1)
#define TFR(r) { x0 += x1; x1 = (x1 << (r)) | (x1 >> (32 - (r))); x1 ^= x0; }
  TFR(13) TFR(15) TFR(26) TFR(6)
  x0 += 1u;          x1 += 0x1BD11BDCu;   // ks1, ks2+1
  TFR(17) TFR(29) TFR(16) TFR(24)
  x0 += 0x1BD11BDBu; x1 += 2u;            // ks2, ks0+2
  TFR(13) TFR(15) TFR(26) TFR(6)
  /* + ks0=0 */      x1 += 4u;            // ks0, ks1+3
  TFR(17) TFR(29) TFR(16) TFR(24)
  x0 += 1u;          x1 += 0x1BD11BDFu;   // ks1, ks2+4
  TFR(13) TFR(15) TFR(26) TFR(6)
  x0 += 0x1BD11BDBu; x1 += 5u;            // ks2, ks0+5
#undef TFR
  o0 = x0; o1 = x1;
}

__device__ __forceinline__ uint32_t threefry_bits_partitionable(uint32_t idx) {
  uint32_t o0, o1;
  threefry2x32_01(0u, idx, o0, o1);
  return o0 ^ o1;
}

// jax.random.normal bit->float (f32): u in [lo,1), eps = sqrt(2)*erfinv(u)
__device__ __forceinline__ float bits_to_normal(uint32_t b) {
  const float lo = -0.99999994f;  // nextafter(-1,0)
  float f = __uint_as_float((b >> 9) | 0x3F800000u) - 1.0f;  // [0,1)
  float u = fmaxf(f * 2.0f + lo, lo);  // (hi-lo) rounds to exactly 2.0f
  return 1.41421356f * erfinvf(u);
}

__device__ __forceinline__ void decode_store(const float (&h3)[60], int t,
                                             const float* __restrict__ s_wd2,
                                             const float* __restrict__ s_bias,
                                             float* __restrict__ out, int n) {
  // traj[t][hh][n][0:4] -> one float4 per (t,hh,n); lane-consecutive n
  float4* trj = (float4*)out + (size_t)(t * 16) * 65536 + n;
  const float4* bd24 = (const float4*)&s_bias[192];
  for (int hh = 0; hh < 16; ++hh) {
    const float4* w0 = (const float4*)&s_wd2[(hh * 4 + 0) * 60];
    const float4* w1r = (const float4*)&s_wd2[(hh * 4 + 1) * 60];
    const float4* w2 = (const float4*)&s_wd2[(hh * 4 + 2) * 60];
    const float4* w3 = (const float4*)&s_wd2[(hh * 4 + 3) * 60];
    float a0 = 0.f, a1 = 0.f, a2 = 0.f, a3 = 0.f;
#pragma unroll
    for (int q = 0; q < 15; ++q) {
      float4 wa = w0[q], wb = w1r[q], wc = w2[q], wdv = w3[q];
      float h0 = h3[4 * q + 0], hv1 = h3[4 * q + 1];
      float hv2 = h3[4 * q + 2], hv3 = h3[4 * q + 3];
      a0 = fmaf(wa.x, h0, a0); a0 = fmaf(wa.y, hv1, a0);
      a0 = fmaf(wa.z, hv2, a0); a0 = fmaf(wa.w, hv3, a0);
      a1 = fmaf(wb.x, h0, a1); a1 = fmaf(wb.y, hv1, a1);
      a1 = fmaf(wb.z, hv2, a1); a1 = fmaf(wb.w, hv3, a1);
      a2 = fmaf(wc.x, h0, a2); a2 = fmaf(wc.y, hv1, a2);
      a2 = fmaf(wc.z, hv2, a2); a2 = fmaf(wc.w, hv3, a2);
      a3 = fmaf(wdv.x, h0, a3); a3 = fmaf(wdv.y, hv1, a3);
      a3 = fmaf(wdv.z, hv2, a3); a3 = fmaf(wdv.w, hv3, a3);
    }
    float4 bb = bd24[hh];
    float4 o;
    o.x = a0 + bb.x; o.y = a1 + bb.y; o.z = a2 + bb.z; o.w = a3 + bb.w;
    trj[(size_t)hh * 65536] = o;
  }
}

// ---------------- Kernel A: encoder -> mu / logvar ----------------
__global__ __launch_bounds__(TPB_A, 1) void vae_encode(
    const float* __restrict__ X,
    const float* __restrict__ w1, const float* __restrict__ b1,
    const float* __restrict__ wm, const float* __restrict__ bm,
    const float* __restrict__ wsd, const float* __restrict__ bsd,
    float* __restrict__ out) {
  __shared__ alignas(16) float s_w1[3840];    // [j][k]  60x64 enc rows
  __shared__ alignas(16) float s_wmst[3840];  // [k][j2] 60x64: mean col|std col
  __shared__ float s_bias[128];               // b1@0 bm@64 bs@96

  const int tid = threadIdx.x;
  const int n = blockIdx.x * TPB_A + tid;

  for (int m = tid; m < 3840; m += TPB_A) s_w1[m] = w1[m];
  for (int m = tid; m < 3840; m += TPB_A) {
    int k = m >> 6, j2 = m & 63;
    s_wmst[m] = (j2 < 32) ? wm[j2 * 60 + k] : wsd[(j2 - 32) * 60 + k];
  }
  if (tid < 60) s_bias[tid] = b1[tid];
  if (tid < 32) { s_bias[64 + tid] = bm[tid]; s_bias[96 + tid] = bsd[tid]; }
  __syncthreads();

  // ---- x: own row, 16x float4 ----
  float x[64];
  {
    const float4* xr = (const float4*)(X + (size_t)n * 64);
#pragma unroll
    for (int q = 0; q < 16; ++q) {
      float4 v = xr[q];
      x[4 * q + 0] = v.x; x[4 * q + 1] = v.y;
      x[4 * q + 2] = v.z; x[4 * q + 3] = v.w;
    }
  }

  // ---- fused encoder + mean/std (identical op order to round-4) ----
  float mu[32], lv[32];
#pragma unroll
  for (int i = 0; i < 32; ++i) { mu[i] = s_bias[64 + i]; lv[i] = s_bias[96 + i]; }
  for (int j = 0; j < 60; ++j) {
    const float4* wr = (const float4*)&s_w1[j * 64];
    float a0 = 0.f, a1 = 0.f, a2 = 0.f, a3 = 0.f;
#pragma unroll
    for (int q = 0; q < 16; ++q) {
      float4 w = wr[q];
      a0 = fmaf(w.x, x[4 * q + 0], a0);
      a1 = fmaf(w.y, x[4 * q + 1], a1);
      a2 = fmaf(w.z, x[4 * q + 2], a2);
      a3 = fmaf(w.w, x[4 * q + 3], a3);
    }
    float h = fmaxf((a0 + a1) + (a2 + a3) + s_bias[j], 0.f);
    const float4* wj = (const float4*)&s_wmst[j * 64];
#pragma unroll
    for (int q = 0; q < 8; ++q) {
      float4 a = wj[q];
      float4 c = wj[q + 8];
      mu[4 * q + 0] = fmaf(a.x, h, mu[4 * q + 0]);
      mu[4 * q + 1] = fmaf(a.y, h, mu[4 * q + 1]);
      mu[4 * q + 2] = fmaf(a.z, h, mu[4 * q + 2]);
      mu[4 * q + 3] = fmaf(a.w, h, mu[4 * q + 3]);
      lv[4 * q + 0] = fmaf(c.x, h, lv[4 * q + 0]);
      lv[4 * q + 1] = fmaf(c.y, h, lv[4 * q + 1]);
      lv[4 * q + 2] = fmaf(c.z, h, lv[4 * q + 2]);
      lv[4 * q + 3] = fmaf(c.w, h, lv[4 * q + 3]);
    }
  }

  // ---- mu / logvar out ----
  float4* muo = (float4*)(out + (size_t)33554432 + (size_t)n * 32);
  float4* lvo = (float4*)(out + (size_t)35651584 + (size_t)n * 32);
#pragma unroll
  for (int g = 0; g < 8; ++g) {
    float4 v; v.x = mu[4 * g + 0]; v.y = mu[4 * g + 1];
    v.z = mu[4 * g + 2]; v.w = mu[4 * g + 3];
    muo[g] = v;
    float4 w; w.x = lv[4 * g + 0]; w.y = lv[4 * g + 1];
    w.z = lv[4 * g + 2]; w.w = lv[4 * g + 3];
    lvo[g] = w;
  }
}

// ---------------- Kernel B: one thread per (n, t) ----------------
__global__ __launch_bounds__(TPB_B, 4) void vae_decode(
    const float* __restrict__ wd1, const float* __restrict__ bd1,
    const float* __restrict__ wd2, const float* __restrict__ bd2,
    float* __restrict__ out) {
  __shared__ alignas(16) float s_d1t[1920];   // [l][j]  32x60 dec1^T rows
  __shared__ alignas(16) float s_wd2[3840];   // [o][k]  64x60 dec2 rows
  __shared__ alignas(16) float s_bias[256];   // bd1@128 bd2@192 (layout kept)

  const int tid = threadIdx.x;
  const int g = blockIdx.x * TPB_B + tid;
  const int n = g & 65535;   // lane-consecutive n -> coalesced traj stores
  const int t = g >> 16;

  for (int m = tid; m < 1920; m += TPB_B) {
    int l = m / 60, j = m - l * 60;
    s_d1t[m] = wd1[j * 32 + l];
  }
  for (int m = tid; m < 3840; m += TPB_B) s_wd2[m] = wd2[m];
  if (tid < 60) s_bias[128 + tid] = bd1[tid];
  if (tid < 64) s_bias[192 + tid] = bd2[tid];
  __syncthreads();

  // ---- z = mu + eps * expf(0.5*lv)  (bit-identical op order) ----
  const float4* mur = (const float4*)(out + (size_t)33554432 + (size_t)n * 32);
  const float4* lvr = (const float4*)(out + (size_t)35651584 + (size_t)n * 32);
  const uint32_t cbase = (uint32_t)t * 2097152u + (uint32_t)n * 32u;
  float z[32];
#pragma unroll
  for (int gq = 0; gq < 8; ++gq) {
    float4 m4 = mur[gq];
    float4 v4 = lvr[gq];
    float s0 = expf(0.5f * v4.x), s1 = expf(0.5f * v4.y);
    float s2 = expf(0.5f * v4.z), s3 = expf(0.5f * v4.w);
    uint32_t c = cbase + (uint32_t)(4 * gq);
    z[4 * gq + 0] = fmaf(bits_to_normal(threefry_bits_partitionable(c + 0u)), s0, m4.x);
    z[4 * gq + 1] = fmaf(bits_to_normal(threefry_bits_partitionable(c + 1u)), s1, m4.y);
    z[4 * gq + 2] = fmaf(bits_to_normal(threefry_bits_partitionable(c + 2u)), s2, m4.z);
    z[4 * gq + 3] = fmaf(bits_to_normal(threefry_bits_partitionable(c + 3u)), s3, m4.w);
  }

  // ---- h3 = relu(dec1 @ z + bd1) ----
  float h3[60];
  {
    const float4* bd14 = (const float4*)&s_bias[128];
#pragma unroll
    for (int q = 0; q < 15; ++q) {
      float4 b = bd14[q];
      h3[4 * q + 0] = b.x; h3[4 * q + 1] = b.y;
      h3[4 * q + 2] = b.z; h3[4 * q + 3] = b.w;
    }
  }
#pragma unroll
  for (int l = 0; l < 32; ++l) {
    float zl = z[l];
    const float4* wr4 = (const float4*)&s_d1t[l * 60];
#pragma unroll
    for (int q = 0; q < 15; ++q) {
      float4 w = wr4[q];
      h3[4 * q + 0] = fmaf(w.x, zl, h3[4 * q + 0]);
      h3[4 * q + 1] = fmaf(w.y, zl, h3[4 * q + 1]);
      h3[4 * q + 2] = fmaf(w.z, zl, h3[4 * q + 2]);
      h3[4 * q + 3] = fmaf(w.w, zl, h3[4 * q + 3]);
    }
  }
#pragma unroll
  for (int j = 0; j < 60; ++j) h3[j] = fmaxf(h3[j], 0.f);

  decode_store(h3, t, s_wd2, s_bias, out, n);

  // ---- prob_list: exactly 1/8 ----
  out[(size_t)37748736 + (size_t)t * 65536 + (size_t)n] = 0.125f;
}

extern "C" void kernel_launch(void* const* d_in, const int* in_sizes, int n_in,
                              void* d_out, int out_size, void* d_ws, size_t ws_size,
                              hipStream_t stream) {
  const float* X   = (const float*)d_in[0];
  // d_in[1] = num_traj (int scalar, fixed == 8)
  const float* w1  = (const float*)d_in[2];
  const float* b1  = (const float*)d_in[3];
  const float* wm  = (const float*)d_in[4];
  const float* bm  = (const float*)d_in[5];
  const float* wsd = (const float*)d_in[6];
  const float* bsd = (const float*)d_in[7];
  const float* wd1 = (const float*)d_in[8];
  const float* bd1 = (const float*)d_in[9];
  const float* wd2 = (const float*)d_in[10];
  const float* bd2 = (const float*)d_in[11];

  vae_encode<<<NBLK_A, TPB_A, 0, stream>>>(X, w1, b1, wm, bm, wsd, bsd,
                                           (float*)d_out);
  vae_decode<<<NBLK_B, TPB_B, 0, stream>>>(wd1, bd1, wd2, bd2, (float*)d_out);
}

// Round 2
// 407.716 us; speedup vs baseline: 1.2531x; 1.2531x over previous
//
#include <hip/hip_runtime.h>
#include <cstdint>

// VAE fused forward, MI355X/gfx950 — f32 in / f32 out.
// N=65536 rows, IO=64, HID=60, LAT=32, T=8.
// Round 6: kill the LDS broadcast bottleneck. Round-5 counters: decode 313us,
// VALUBusy 51%, HBM 38% -> neither saturated; ~1460 wave-uniform ds_read_b128
// per wave occupied the per-CU LDS return path (~10cyc each, ~195us/CU).
// Fix: no LDS at all — weights are read with wave-uniform addresses straight
// from global, which the compiler scalarizes to s_load_* through the constant
// cache (scalar pipe, free broadcast, hidden under VALU issue).
// All arithmetic is bit-identical to round 5: same fmaf chains/order, same
// threefry/erfinv/expf. dec1 re-formed row-wise (h3[j] = bd1[j] + sum_l) which
// preserves the exact per-element accumulation order.
// RNG: JAX partitionable threefry, key (0,1): per flat index i,
//   bits = o0^o1 of threefry2x32(c0=0, c1=i);
//   u = max(lo,(f32(bits>>9|0x3F800000)-1)*2+lo), eps = sqrt(2)*erfinvf(u).
// Output (f32): traj[8][16][65536][4] @0 | mu[65536][32] @33554432 |
//   logvar[65536][32] @35651584 | prob[8][4096][16] @37748736 (== 0.125f).

#define TPB_A 256
#define NBLK_A 256
#define TPB_B 256
#define NBLK_B 2048

// JAX threefry2x32 with key (0,1): ks = {0, 1, 0^1^0x1BD11BDA = 0x1BD11BDB}
__device__ __forceinline__ void threefry2x32_01(uint32_t c0, uint32_t c1,
                                                uint32_t& o0, uint32_t& o1) {
  uint32_t x0 = c0;        // + ks0 (0)
  uint32_t x1 = c1 + 1u;   // + ks1 (1)
#define TFR(r) { x0 += x1; x1 = (x1 << (r)) | (x1 >> (32 - (r))); x1 ^= x0; }
  TFR(13) TFR(15) TFR(26) TFR(6)
  x0 += 1u;          x1 += 0x1BD11BDCu;   // ks1, ks2+1
  TFR(17) TFR(29) TFR(16) TFR(24)
  x0 += 0x1BD11BDBu; x1 += 2u;            // ks2, ks0+2
  TFR(13) TFR(15) TFR(26) TFR(6)
  /* + ks0=0 */      x1 += 4u;            // ks0, ks1+3
  TFR(17) TFR(29) TFR(16) TFR(24)
  x0 += 1u;          x1 += 0x1BD11BDFu;   // ks1, ks2+4
  TFR(13) TFR(15) TFR(26) TFR(6)
  x0 += 0x1BD11BDBu; x1 += 5u;            // ks2, ks0+5
#undef TFR
  o0 = x0; o1 = x1;
}

__device__ __forceinline__ uint32_t threefry_bits_partitionable(uint32_t idx) {
  uint32_t o0, o1;
  threefry2x32_01(0u, idx, o0, o1);
  return o0 ^ o1;
}

// jax.random.normal bit->float (f32): u in [lo,1), eps = sqrt(2)*erfinv(u)
__device__ __forceinline__ float bits_to_normal(uint32_t b) {
  const float lo = -0.99999994f;  // nextafter(-1,0)
  float f = __uint_as_float((b >> 9) | 0x3F800000u) - 1.0f;  // [0,1)
  float u = fmaxf(f * 2.0f + lo, lo);  // (hi-lo) rounds to exactly 2.0f
  return 1.41421356f * erfinvf(u);
}

// ---------------- Kernel A: encoder -> mu / logvar ----------------
// 1 thread/row, grid-limited to 1 wave/SIMD; weights via scalar loads.
__global__ __launch_bounds__(TPB_A, 1) void vae_encode(
    const float* __restrict__ X,
    const float* __restrict__ w1, const float* __restrict__ b1,
    const float* __restrict__ wm, const float* __restrict__ bm,
    const float* __restrict__ wsd, const float* __restrict__ bsd,
    float* __restrict__ out) {
  const int tid = threadIdx.x;
  const int n = blockIdx.x * TPB_A + tid;

  // ---- x: own row, 16x float4 (vector loads, coalesced) ----
  float x[64];
  {
    const float4* xr = (const float4*)(X + (size_t)n * 64);
#pragma unroll
    for (int q = 0; q < 16; ++q) {
      float4 v = xr[q];
      x[4 * q + 0] = v.x; x[4 * q + 1] = v.y;
      x[4 * q + 2] = v.z; x[4 * q + 3] = v.w;
    }
  }

  // ---- fused encoder + mean/std (identical op order to round-5) ----
  // Per j: h_j from w1 row j (uniform -> s_load), then scatter into mu/lv
  // with wm/wsd column j (uniform strided s_load_dword, K$-line-reused
  // across 16 consecutive j).
  float mu[32], lv[32];
#pragma unroll
  for (int i = 0; i < 32; ++i) { mu[i] = bm[i]; lv[i] = bsd[i]; }
  for (int j = 0; j < 60; ++j) {
    const float4* wr = (const float4*)(w1 + j * 64);  // uniform row
    float a0 = 0.f, a1 = 0.f, a2 = 0.f, a3 = 0.f;
#pragma unroll
    for (int q = 0; q < 16; ++q) {
      float4 w = wr[q];
      a0 = fmaf(w.x, x[4 * q + 0], a0);
      a1 = fmaf(w.y, x[4 * q + 1], a1);
      a2 = fmaf(w.z, x[4 * q + 2], a2);
      a3 = fmaf(w.w, x[4 * q + 3], a3);
    }
    float h = fmaxf((a0 + a1) + (a2 + a3) + b1[j], 0.f);
    const float* wmc = wm + j;   // column j, stride 60 (uniform)
    const float* wsc = wsd + j;
#pragma unroll
    for (int i = 0; i < 32; ++i) {
      mu[i] = fmaf(wmc[i * 60], h, mu[i]);
      lv[i] = fmaf(wsc[i * 60], h, lv[i]);
    }
  }

  // ---- mu / logvar out ----
  float4* muo = (float4*)(out + (size_t)33554432 + (size_t)n * 32);
  float4* lvo = (float4*)(out + (size_t)35651584 + (size_t)n * 32);
#pragma unroll
  for (int g = 0; g < 8; ++g) {
    float4 v; v.x = mu[4 * g + 0]; v.y = mu[4 * g + 1];
    v.z = mu[4 * g + 2]; v.w = mu[4 * g + 3];
    muo[g] = v;
    float4 w; w.x = lv[4 * g + 0]; w.y = lv[4 * g + 1];
    w.z = lv[4 * g + 2]; w.w = lv[4 * g + 3];
    lvo[g] = w;
  }
}

// ---------------- Kernel B: one thread per (n, t) ----------------
// No LDS; dec1/dec2 weights + biases via wave-uniform scalar loads.
__global__ __launch_bounds__(TPB_B, 4) void vae_decode(
    const float* __restrict__ wd1, const float* __restrict__ bd1,
    const float* __restrict__ wd2, const float* __restrict__ bd2,
    float* __restrict__ out) {
  const int tid = threadIdx.x;
  const int g = blockIdx.x * TPB_B + tid;
  const int n = g & 65535;   // lane-consecutive n -> coalesced traj stores
  const int t = g >> 16;

  // ---- z = mu + eps * expf(0.5*lv)  (bit-identical op order) ----
  const float4* mur = (const float4*)(out + (size_t)33554432 + (size_t)n * 32);
  const float4* lvr = (const float4*)(out + (size_t)35651584 + (size_t)n * 32);
  const uint32_t cbase = (uint32_t)t * 2097152u + (uint32_t)n * 32u;
  float z[32];
#pragma unroll
  for (int gq = 0; gq < 8; ++gq) {
    float4 m4 = mur[gq];
    float4 v4 = lvr[gq];
    float s0 = expf(0.5f * v4.x), s1 = expf(0.5f * v4.y);
    float s2 = expf(0.5f * v4.z), s3 = expf(0.5f * v4.w);
    uint32_t c = cbase + (uint32_t)(4 * gq);
    z[4 * gq + 0] = fmaf(bits_to_normal(threefry_bits_partitionable(c + 0u)), s0, m4.x);
    z[4 * gq + 1] = fmaf(bits_to_normal(threefry_bits_partitionable(c + 1u)), s1, m4.y);
    z[4 * gq + 2] = fmaf(bits_to_normal(threefry_bits_partitionable(c + 2u)), s2, m4.z);
    z[4 * gq + 3] = fmaf(bits_to_normal(threefry_bits_partitionable(c + 3u)), s3, m4.w);
  }

  // ---- h3 = relu(dec1 @ z + bd1), row form ----
  // h3[j] = relu(bd1[j] + sum_{l=0..31} wd1[j][l]*z[l]) — same accumulation
  // order as the round-5 scatter form (bias first, then l ascending).
  float h3[60];
#pragma unroll
  for (int j = 0; j < 60; ++j) {
    const float* wj = wd1 + j * 32;   // uniform contiguous row (128B)
    float a = bd1[j];
#pragma unroll
    for (int l = 0; l < 32; ++l) a = fmaf(wj[l], z[l], a);
    h3[j] = fmaxf(a, 0.f);
  }

  // ---- dec2 + store: traj[t][hh][n][0:4], one float4 per (t,hh,n) ----
  {
    float4* trj = (float4*)out + (size_t)(t * 16) * 65536 + n;
    const float4* bd24 = (const float4*)bd2;
    for (int hh = 0; hh < 16; ++hh) {
      const float4* w0 = (const float4*)(wd2 + (hh * 4 + 0) * 60);
      const float4* w1r = (const float4*)(wd2 + (hh * 4 + 1) * 60);
      const float4* w2 = (const float4*)(wd2 + (hh * 4 + 2) * 60);
      const float4* w3 = (const float4*)(wd2 + (hh * 4 + 3) * 60);
      float a0 = 0.f, a1 = 0.f, a2 = 0.f, a3 = 0.f;
#pragma unroll
      for (int q = 0; q < 15; ++q) {
        float4 wa = w0[q], wb = w1r[q], wc = w2[q], wdv = w3[q];
        float h0 = h3[4 * q + 0], hv1 = h3[4 * q + 1];
        float hv2 = h3[4 * q + 2], hv3 = h3[4 * q + 3];
        a0 = fmaf(wa.x, h0, a0); a0 = fmaf(wa.y, hv1, a0);
        a0 = fmaf(wa.z, hv2, a0); a0 = fmaf(wa.w, hv3, a0);
        a1 = fmaf(wb.x, h0, a1); a1 = fmaf(wb.y, hv1, a1);
        a1 = fmaf(wb.z, hv2, a1); a1 = fmaf(wb.w, hv3, a1);
        a2 = fmaf(wc.x, h0, a2); a2 = fmaf(wc.y, hv1, a2);
        a2 = fmaf(wc.z, hv2, a2); a2 = fmaf(wc.w, hv3, a2);
        a3 = fmaf(wdv.x, h0, a3); a3 = fmaf(wdv.y, hv1, a3);
        a3 = fmaf(wdv.z, hv2, a3); a3 = fmaf(wdv.w, hv3, a3);
      }
      float4 bb = bd24[hh];
      float4 o;
      o.x = a0 + bb.x; o.y = a1 + bb.y; o.z = a2 + bb.z; o.w = a3 + bb.w;
      trj[(size_t)hh * 65536] = o;
    }
  }

  // ---- prob_list: exactly 1/8 ----
  out[(size_t)37748736 + (size_t)t * 65536 + (size_t)n] = 0.125f;
}

extern "C" void kernel_launch(void* const* d_in, const int* in_sizes, int n_in,
                              void* d_out, int out_size, void* d_ws, size_t ws_size,
                              hipStream_t stream) {
  const float* X   = (const float*)d_in[0];
  // d_in[1] = num_traj (int scalar, fixed == 8)
  const float* w1  = (const float*)d_in[2];
  const float* b1  = (const float*)d_in[3];
  const float* wm  = (const float*)d_in[4];
  const float* bm  = (const float*)d_in[5];
  const float* wsd = (const float*)d_in[6];
  const float* bsd = (const float*)d_in[7];
  const float* wd1 = (const float*)d_in[8];
  const float* bd1 = (const float*)d_in[9];
  const float* wd2 = (const float*)d_in[10];
  const float* bd2 = (const float*)d_in[11];

  vae_encode<<<NBLK_A, TPB_A, 0, stream>>>(X, w1, b1, wm, bm, wsd, bsd,
                                           (float*)d_out);
  vae_decode<<<NBLK_B, TPB_B, 0, stream>>>(wd1, bd1, wd2, bd2, (float*)d_out);
}

// Round 3
// 388.013 us; speedup vs baseline: 1.3167x; 1.0508x over previous
//
#include <hip/hip_runtime.h>
#include <cstdint>

// VAE fused forward, MI355X/gfx950 — f32 in / f32 out.
// N=65536 rows, IO=64, HID=60, LAT=32, T=8.
// Round 7: encoder occupancy. R6 counters: decode 208us (VALU 66%) but encode
// stuck ~200us — it was 1 wave/SIMD (65536 threads) with ~4800 SMEM ops/wave,
// pure latency exposure. Fix: 4 waves per 64 rows; each wave recomputes the
// h-chain but scatters only 8 of 32 mu/lv outputs (wave-uniform slot via
// readfirstlane -> weight reads stay scalar s_loads). 4096 waves = 4/SIMD.
// Bit-exact: every mu[i]/lv[i] is still bias + fmaf over j ascending with
// identical h values; decode kernel unchanged from R6.
// RNG: JAX partitionable threefry, key (0,1): per flat index i,
//   bits = o0^o1 of threefry2x32(c0=0, c1=i);
//   u = max(lo,(f32(bits>>9|0x3F800000)-1)*2+lo), eps = sqrt(2)*erfinvf(u).
// Output (f32): traj[8][16][65536][4] @0 | mu[65536][32] @33554432 |
//   logvar[65536][32] @35651584 | prob[8][4096][16] @37748736 (== 0.125f).

#define TPB_A 256
#define NBLK_A 1024   // 64 rows/block x 4 slot-waves
#define TPB_B 256
#define NBLK_B 2048

// JAX threefry2x32 with key (0,1): ks = {0, 1, 0^1^0x1BD11BDA = 0x1BD11BDB}
__device__ __forceinline__ void threefry2x32_01(uint32_t c0, uint32_t c1,
                                                uint32_t& o0, uint32_t& o1) {
  uint32_t x0 = c0;        // + ks0 (0)
  uint32_t x1 = c1 + 1u;   // + ks1 (1)
#define TFR(r) { x0 += x1; x1 = (x1 << (r)) | (x1 >> (32 - (r))); x1 ^= x0; }
  TFR(13) TFR(15) TFR(26) TFR(6)
  x0 += 1u;          x1 += 0x1BD11BDCu;   // ks1, ks2+1
  TFR(17) TFR(29) TFR(16) TFR(24)
  x0 += 0x1BD11BDBu; x1 += 2u;            // ks2, ks0+2
  TFR(13) TFR(15) TFR(26) TFR(6)
  /* + ks0=0 */      x1 += 4u;            // ks0, ks1+3
  TFR(17) TFR(29) TFR(16) TFR(24)
  x0 += 1u;          x1 += 0x1BD11BDFu;   // ks1, ks2+4
  TFR(13) TFR(15) TFR(26) TFR(6)
  x0 += 0x1BD11BDBu; x1 += 5u;            // ks2, ks0+5
#undef TFR
  o0 = x0; o1 = x1;
}

__device__ __forceinline__ uint32_t threefry_bits_partitionable(uint32_t idx) {
  uint32_t o0, o1;
  threefry2x32_01(0u, idx, o0, o1);
  return o0 ^ o1;
}

// jax.random.normal bit->float (f32): u in [lo,1), eps = sqrt(2)*erfinv(u)
__device__ __forceinline__ float bits_to_normal(uint32_t b) {
  const float lo = -0.99999994f;  // nextafter(-1,0)
  float f = __uint_as_float((b >> 9) | 0x3F800000u) - 1.0f;  // [0,1)
  float u = fmaxf(f * 2.0f + lo, lo);  // (hi-lo) rounds to exactly 2.0f
  return 1.41421356f * erfinvf(u);
}

// ---------------- Kernel A: encoder -> mu / logvar ----------------
// 64 rows per block; 4 waves each own an 8-wide latent slot. h recomputed
// per wave (cheap), weight reads wave-uniform -> scalar pipe.
__global__ __launch_bounds__(TPB_A, 4) void vae_encode(
    const float* __restrict__ X,
    const float* __restrict__ w1, const float* __restrict__ b1,
    const float* __restrict__ wm, const float* __restrict__ bm,
    const float* __restrict__ wsd, const float* __restrict__ bsd,
    float* __restrict__ out) {
  const int tid = threadIdx.x;
  const int lane = tid & 63;
  const int slot = __builtin_amdgcn_readfirstlane(tid >> 6);  // 0..3, SGPR
  const int i0 = slot * 8;
  const int n = blockIdx.x * 64 + lane;

  // ---- x: own row, 16x float4 (coalesced within the wave) ----
  float x[64];
  {
    const float4* xr = (const float4*)(X + (size_t)n * 64);
#pragma unroll
    for (int q = 0; q < 16; ++q) {
      float4 v = xr[q];
      x[4 * q + 0] = v.x; x[4 * q + 1] = v.y;
      x[4 * q + 2] = v.z; x[4 * q + 3] = v.w;
    }
  }

  // ---- fused encoder + mean/std, slot-restricted scatter ----
  float mu[8], lv[8];
#pragma unroll
  for (int ii = 0; ii < 8; ++ii) { mu[ii] = bm[i0 + ii]; lv[ii] = bsd[i0 + ii]; }
  for (int j = 0; j < 60; ++j) {
    const float4* wr = (const float4*)(w1 + j * 64);  // uniform row
    float a0 = 0.f, a1 = 0.f, a2 = 0.f, a3 = 0.f;
#pragma unroll
    for (int q = 0; q < 16; ++q) {
      float4 w = wr[q];
      a0 = fmaf(w.x, x[4 * q + 0], a0);
      a1 = fmaf(w.y, x[4 * q + 1], a1);
      a2 = fmaf(w.z, x[4 * q + 2], a2);
      a3 = fmaf(w.w, x[4 * q + 3], a3);
    }
    float h = fmaxf((a0 + a1) + (a2 + a3) + b1[j], 0.f);
    const float* wmc = wm + i0 * 60 + j;   // uniform, stride-60 walk
    const float* wsc = wsd + i0 * 60 + j;
#pragma unroll
    for (int ii = 0; ii < 8; ++ii) {
      mu[ii] = fmaf(wmc[ii * 60], h, mu[ii]);
      lv[ii] = fmaf(wsc[ii * 60], h, lv[ii]);
    }
  }

  // ---- mu / logvar out: 32B contiguous per lane ----
  float4* muo = (float4*)(out + (size_t)33554432 + (size_t)n * 32 + i0);
  float4* lvo = (float4*)(out + (size_t)35651584 + (size_t)n * 32 + i0);
  float4 v0, v1, w0, w1v;
  v0.x = mu[0]; v0.y = mu[1]; v0.z = mu[2]; v0.w = mu[3];
  v1.x = mu[4]; v1.y = mu[5]; v1.z = mu[6]; v1.w = mu[7];
  w0.x = lv[0]; w0.y = lv[1]; w0.z = lv[2]; w0.w = lv[3];
  w1v.x = lv[4]; w1v.y = lv[5]; w1v.z = lv[6]; w1v.w = lv[7];
  muo[0] = v0; muo[1] = v1;
  lvo[0] = w0; lvo[1] = w1v;
}

// ---------------- Kernel B: one thread per (n, t) ----------------
// No LDS; dec1/dec2 weights + biases via wave-uniform scalar loads.
__global__ __launch_bounds__(TPB_B, 4) void vae_decode(
    const float* __restrict__ wd1, const float* __restrict__ bd1,
    const float* __restrict__ wd2, const float* __restrict__ bd2,
    float* __restrict__ out) {
  const int tid = threadIdx.x;
  const int g = blockIdx.x * TPB_B + tid;
  const int n = g & 65535;   // lane-consecutive n -> coalesced traj stores
  const int t = g >> 16;

  // ---- z = mu + eps * expf(0.5*lv)  (bit-identical op order) ----
  const float4* mur = (const float4*)(out + (size_t)33554432 + (size_t)n * 32);
  const float4* lvr = (const float4*)(out + (size_t)35651584 + (size_t)n * 32);
  const uint32_t cbase = (uint32_t)t * 2097152u + (uint32_t)n * 32u;
  float z[32];
#pragma unroll
  for (int gq = 0; gq < 8; ++gq) {
    float4 m4 = mur[gq];
    float4 v4 = lvr[gq];
    float s0 = expf(0.5f * v4.x), s1 = expf(0.5f * v4.y);
    float s2 = expf(0.5f * v4.z), s3 = expf(0.5f * v4.w);
    uint32_t c = cbase + (uint32_t)(4 * gq);
    z[4 * gq + 0] = fmaf(bits_to_normal(threefry_bits_partitionable(c + 0u)), s0, m4.x);
    z[4 * gq + 1] = fmaf(bits_to_normal(threefry_bits_partitionable(c + 1u)), s1, m4.y);
    z[4 * gq + 2] = fmaf(bits_to_normal(threefry_bits_partitionable(c + 2u)), s2, m4.z);
    z[4 * gq + 3] = fmaf(bits_to_normal(threefry_bits_partitionable(c + 3u)), s3, m4.w);
  }

  // ---- h3 = relu(dec1 @ z + bd1), row form ----
  float h3[60];
#pragma unroll
  for (int j = 0; j < 60; ++j) {
    const float* wj = wd1 + j * 32;   // uniform contiguous row (128B)
    float a = bd1[j];
#pragma unroll
    for (int l = 0; l < 32; ++l) a = fmaf(wj[l], z[l], a);
    h3[j] = fmaxf(a, 0.f);
  }

  // ---- dec2 + store: traj[t][hh][n][0:4], one float4 per (t,hh,n) ----
  {
    float4* trj = (float4*)out + (size_t)(t * 16) * 65536 + n;
    const float4* bd24 = (const float4*)bd2;
    for (int hh = 0; hh < 16; ++hh) {
      const float4* w0 = (const float4*)(wd2 + (hh * 4 + 0) * 60);
      const float4* w1r = (const float4*)(wd2 + (hh * 4 + 1) * 60);
      const float4* w2 = (const float4*)(wd2 + (hh * 4 + 2) * 60);
      const float4* w3 = (const float4*)(wd2 + (hh * 4 + 3) * 60);
      float a0 = 0.f, a1 = 0.f, a2 = 0.f, a3 = 0.f;
#pragma unroll
      for (int q = 0; q < 15; ++q) {
        float4 wa = w0[q], wb = w1r[q], wc = w2[q], wdv = w3[q];
        float h0 = h3[4 * q + 0], hv1 = h3[4 * q + 1];
        float hv2 = h3[4 * q + 2], hv3 = h3[4 * q + 3];
        a0 = fmaf(wa.x, h0, a0); a0 = fmaf(wa.y, hv1, a0);
        a0 = fmaf(wa.z, hv2, a0); a0 = fmaf(wa.w, hv3, a0);
        a1 = fmaf(wb.x, h0, a1); a1 = fmaf(wb.y, hv1, a1);
        a1 = fmaf(wb.z, hv2, a1); a1 = fmaf(wb.w, hv3, a1);
        a2 = fmaf(wc.x, h0, a2); a2 = fmaf(wc.y, hv1, a2);
        a2 = fmaf(wc.z, hv2, a2); a2 = fmaf(wc.w, hv3, a2);
        a3 = fmaf(wdv.x, h0, a3); a3 = fmaf(wdv.y, hv1, a3);
        a3 = fmaf(wdv.z, hv2, a3); a3 = fmaf(wdv.w, hv3, a3);
      }
      float4 bb = bd24[hh];
      float4 o;
      o.x = a0 + bb.x; o.y = a1 + bb.y; o.z = a2 + bb.z; o.w = a3 + bb.w;
      trj[(size_t)hh * 65536] = o;
    }
  }

  // ---- prob_list: exactly 1/8 ----
  out[(size_t)37748736 + (size_t)t * 65536 + (size_t)n] = 0.125f;
}

extern "C" void kernel_launch(void* const* d_in, const int* in_sizes, int n_in,
                              void* d_out, int out_size, void* d_ws, size_t ws_size,
                              hipStream_t stream) {
  const float* X   = (const float*)d_in[0];
  // d_in[1] = num_traj (int scalar, fixed == 8)
  const float* w1  = (const float*)d_in[2];
  const float* b1  = (const float*)d_in[3];
  const float* wm  = (const float*)d_in[4];
  const float* bm  = (const float*)d_in[5];
  const float* wsd = (const float*)d_in[6];
  const float* bsd = (const float*)d_in[7];
  const float* wd1 = (const float*)d_in[8];
  const float* bd1 = (const float*)d_in[9];
  const float* wd2 = (const float*)d_in[10];
  const float* bd2 = (const float*)d_in[11];

  vae_encode<<<NBLK_A, TPB_A, 0, stream>>>(X, w1, b1, wm, bm, wsd, bsd,
                                           (float*)d_out);
  vae_decode<<<NBLK_B, TPB_B, 0, stream>>>(wd1, bd1, wd2, bd2, (float*)d_out);
}